// Round 5
// baseline (231.011 us; speedup 1.0000x reference)
//
#include <hip/hip_runtime.h>

// Scaled dot-product attention, B=4 H=16 S=2048 D=64, fp32 in/out.
// R11 = R10 resubmitted verbatim (R10 bench was an infra failure:
// "MI355X container failed twice", no compile/correctness signal; source
// audited for OOB/alignment -- clean).
// R10: (a) prep_kernel rewritten -- old version had a 16-way LDS bank
// conflict on every V ds_write (column writes at row-stride 64 f16 put all
// 16 lanes of a quarter-wave on one bank) and 128B-segmented vt writes;
// complement (dur_us - fa) ~110us vs ~20us traffic roofline. New prep:
// 128s x 64d tiles, fused K-convert, V-transpose via LDS [d][slot] with
// stride-132 f16 (4-way max), sp-perm at LDS write, 256B-coalesced vt
// stores. (b) fa COMPUTE reordered (T15-lite): exp-B interleaved with
// PV-A MFMAs, V frags hoisted to regs shared by PV-A/PV-B -- half the
// transcendental work hides under the matrix pipe. Same math, same
// accumulation order (bitwise identical). Ping-pong pipeline unchanged.

#define S_LEN 2048
#define D_DIM 64
#define N_BH  64
#define QSCALE 0.18033688011112042f  // (1/sqrt(64)) * log2(e)

typedef _Float16 half8 __attribute__((ext_vector_type(8)));
typedef _Float16 half4 __attribute__((ext_vector_type(4)));
typedef float floatx16 __attribute__((ext_vector_type(16)));
typedef unsigned int uint4v __attribute__((ext_vector_type(4)));

#define MFMA32(a, b, c) __builtin_amdgcn_mfma_f32_32x32x16_f16((a), (b), (c), 0, 0, 0)

#define GLL16(g, l) __builtin_amdgcn_global_load_lds(                      \
    (const __attribute__((address_space(1))) void*)(g),                    \
    (__attribute__((address_space(3))) void*)(l), 16, 0, 0)

// ---- pre-pass: K fp32 -> f16 (same layout, streaming); V fp32 -> f16
// transposed to [bh][d][s'] where s' = s with bits 2<->3 swapped.
// Tile 128s x 64d. LDS [d][slot] stride 132 f16: column-writes land on
// banks (8*lane + 2j + slot/2)%32 -> 4-way max (was 16-way at stride 64).
// vt stores: 16 lanes cover one d-row's 16 chunks -> 256B contiguous/row.
__global__ __launch_bounds__(256) void prep_kernel(
    const float* __restrict__ kg, const float* __restrict__ vg,
    _Float16* __restrict__ kh, _Float16* __restrict__ vt)
{
    __shared__ _Float16 Ls[64 * 132];
    const int tid = threadIdx.x;
    const int bh = blockIdx.y;
    const int sbase = blockIdx.x * 128;
    const size_t gbase = ((size_t)(bh * S_LEN + sbase)) * D_DIM;  // 8192 floats

    // K: pure convert, fully coalesced both sides.
#pragma unroll
    for (int i = 0; i < 8; ++i) {
        const int e = i * 1024 + tid * 4;
        const float4 kv = *(const float4*)(kg + gbase + e);
        half4 hk;
        hk[0] = (_Float16)kv.x; hk[1] = (_Float16)kv.y;
        hk[2] = (_Float16)kv.z; hk[3] = (_Float16)kv.w;
        *(half4*)(kh + gbase + e) = hk;
    }
    // V: coalesced load, transposed scalar LDS write at sp-permuted slot.
#pragma unroll
    for (int i = 0; i < 8; ++i) {
        const int e = i * 1024 + tid * 4;
        const int s = e >> 6, d0 = e & 63;
        const float4 vv = *(const float4*)(vg + gbase + e);
        const int sp = (s & ~12) | ((s & 4) << 1) | ((s & 8) >> 1);  // b2<->b3
        Ls[(d0 + 0) * 132 + sp] = (_Float16)vv.x;
        Ls[(d0 + 1) * 132 + sp] = (_Float16)vv.y;
        Ls[(d0 + 2) * 132 + sp] = (_Float16)vv.z;
        Ls[(d0 + 3) * 132 + sp] = (_Float16)vv.w;
    }
    __syncthreads();
    // write out: 64 d-rows x 128 f16; wave w owns rows [w*16, w*16+16).
    const int w = tid >> 6, L = tid & 63;
    const int dr = L >> 4;        // row within 4-row group
    const int c  = L & 15;        // 16B chunk within row
#pragma unroll
    for (int k = 0; k < 4; ++k) {
        const int d = w * 16 + k * 4 + dr;
        // stride 132 f16 = 264B: 8B-aligned for all d -> two b64 reads
        const half4 lo = *(const half4*)&Ls[d * 132 + c * 8];
        const half4 hi = *(const half4*)&Ls[d * 132 + c * 8 + 4];
        half8 o;
        o[0] = lo[0]; o[1] = lo[1]; o[2] = lo[2]; o[3] = lo[3];
        o[4] = hi[0]; o[5] = hi[1]; o[6] = hi[2]; o[7] = hi[3];
        *(half8*)(vt + ((size_t)(bh * D_DIM + d)) * S_LEN + sbase + c * 8) = o;
    }
}

// ---- main flash kernel: 4 waves x 64 q = 256 q per block; K-tiles of 64
__global__ __launch_bounds__(256, 2) void fa_kernel(
    const float* __restrict__ qg, const _Float16* __restrict__ kh,
    const _Float16* __restrict__ vt, float* __restrict__ outg)
{
    // Static double buffers. [row][phys 16B chunk], phys = logical ^ (row&7).
    __shared__ _Float16 Kl0[64 * 64];   // [key][d]
    __shared__ _Float16 Kl1[64 * 64];
    __shared__ _Float16 Vl0[64 * 64];   // [d][pos]  (pos = permuted key)
    __shared__ _Float16 Vl1[64 * 64];

    const int tid = threadIdx.x;
    const int w = tid >> 6;            // wave 0..3
    const int L = tid & 63;
    const int lq = L & 31;
    const int h = L >> 5;

    // 512 blocks; XCD ~ id&7 -> bh 8c..8c+7 on XCD c (4MB f16 KV fits L2)
    const int id = blockIdx.x;
    const int bh   = ((id & 7) << 3) | (id >> 6);
    const int qblk = (id >> 3) & 7;    // 8 q-blocks of 256 q
    const int qrowA = qblk * 256 + w * 32 + lq;

    // Q fragments (B operand of S^T): B[k=d][n=q], k = 16*ks + 8*h + j
    half8 qbA[4], qbB[4];
    {
        const float* qpA = qg + ((size_t)bh * S_LEN + qrowA) * D_DIM + h * 8;
        const float* qpB = qpA + 128 * D_DIM;
#pragma unroll
        for (int ks = 0; ks < 4; ++ks) {
            const float4 a0 = *(const float4*)(qpA + ks * 16);
            const float4 b0 = *(const float4*)(qpA + ks * 16 + 4);
            const float4 a1 = *(const float4*)(qpB + ks * 16);
            const float4 b1 = *(const float4*)(qpB + ks * 16 + 4);
            qbA[ks][0] = (_Float16)(a0.x * QSCALE);
            qbA[ks][1] = (_Float16)(a0.y * QSCALE);
            qbA[ks][2] = (_Float16)(a0.z * QSCALE);
            qbA[ks][3] = (_Float16)(a0.w * QSCALE);
            qbA[ks][4] = (_Float16)(b0.x * QSCALE);
            qbA[ks][5] = (_Float16)(b0.y * QSCALE);
            qbA[ks][6] = (_Float16)(b0.z * QSCALE);
            qbA[ks][7] = (_Float16)(b0.w * QSCALE);
            qbB[ks][0] = (_Float16)(a1.x * QSCALE);
            qbB[ks][1] = (_Float16)(a1.y * QSCALE);
            qbB[ks][2] = (_Float16)(a1.z * QSCALE);
            qbB[ks][3] = (_Float16)(a1.w * QSCALE);
            qbB[ks][4] = (_Float16)(b1.x * QSCALE);
            qbB[ks][5] = (_Float16)(b1.y * QSCALE);
            qbB[ks][6] = (_Float16)(b1.z * QSCALE);
            qbB[ks][7] = (_Float16)(b1.w * QSCALE);
        }
    }

    floatx16 o0A, o1A, lacA, o0B, o1B, lacB;
#pragma unroll
    for (int r = 0; r < 16; ++r) {
        o0A[r] = 0.f; o1A[r] = 0.f; lacA[r] = 0.f;
        o0B[r] = 0.f; o1B[r] = 0.f; lacB[r] = 0.f;
    }

    half8 ones;
#pragma unroll
    for (int j = 0; j < 8; ++j) ones[j] = (_Float16)1.0f;

    // staging: wave w covers rows [w*16, w*16+16), 2 GLL16 each for K and V.
    const int rloc = L >> 3, lc = L & 7;
    const int crd = lc ^ rloc;
    const _Float16* kgl = kh + (size_t)bh * S_LEN * D_DIM
                        + (size_t)(w * 16 + rloc) * D_DIM + crd * 8;
    const _Float16* vgl = vt + (size_t)bh * D_DIM * S_LEN
                        + (size_t)(w * 16 + rloc) * S_LEN + crd * 8;
    const int woff = w * 16 * 64;

#define STAGE(KD, VD) do {                                                 \
        GLL16(kgl,                     &KD[woff]);                         \
        GLL16(kgl + (size_t)8 * D_DIM, &KD[woff + 8 * 64]);                \
        GLL16(vgl,                     &VD[woff]);                         \
        GLL16(vgl + (size_t)8 * S_LEN, &VD[woff + 8 * 64]);                \
        kgl += 64 * D_DIM;                                                 \
        vgl += 64;                                                         \
    } while (0)

    // one exp-B step: 4 exp2 + 2 cvt_pkrtz (interleaves with one MFMA)
#define EXPB(p) do {                                                       \
        const auto eB0 = __builtin_amdgcn_cvt_pkrtz(                       \
            __builtin_amdgcn_exp2f(s0B[2 * (p)]),                          \
            __builtin_amdgcn_exp2f(s0B[2 * (p) + 1]));                     \
        const auto eB1 = __builtin_amdgcn_cvt_pkrtz(                       \
            __builtin_amdgcn_exp2f(s1B[2 * (p)]),                          \
            __builtin_amdgcn_exp2f(s1B[2 * (p) + 1]));                     \
        pkB0[p] = __builtin_bit_cast(unsigned int, eB0);                   \
        pkB1[p] = __builtin_bit_cast(unsigned int, eB1);                   \
    } while (0)

#define COMPUTE(KB, VB) do {                                               \
        /* Phase 1: S^T = K Q^T both groups; K fragments read ONCE */      \
        floatx16 s0A, s1A, s0B, s1B;                                       \
        _Pragma("unroll")                                                  \
        for (int r = 0; r < 16; ++r) {                                     \
            s0A[r] = 0.f; s1A[r] = 0.f; s0B[r] = 0.f; s1B[r] = 0.f;        \
        }                                                                  \
        _Pragma("unroll")                                                  \
        for (int ks = 0; ks < 4; ++ks) {                                   \
            const int sw = (((2 * ks + h) ^ (lq & 7)) << 3);               \
            const half8 ka0 = *(const half8*)&KB[lq * 64 + sw];            \
            const half8 ka1 = *(const half8*)&KB[(32 + lq) * 64 + sw];     \
            s0A = MFMA32(ka0, qbA[ks], s0A);                               \
            s1A = MFMA32(ka1, qbA[ks], s1A);                               \
            s0B = MFMA32(ka0, qbB[ks], s0B);                               \
            s1B = MFMA32(ka1, qbB[ks], s1B);                               \
        }                                                                  \
        /* hoist V fragments (shared by PV-A and PV-B); reads overlap */   \
        half8 vbl[4], vbh[4];                                              \
        _Pragma("unroll")                                                  \
        for (int ksg = 0; ksg < 4; ++ksg) {                                \
            const int sw = (((2 * ksg + h) ^ (lq & 7)) << 3);              \
            vbl[ksg] = *(const half8*)&VB[lq * 64 + sw];                   \
            vbh[ksg] = *(const half8*)&VB[(32 + lq) * 64 + sw];            \
        }                                                                  \
        /* Phase 2: exp-A (overlaps the V ds_read latency) */              \
        unsigned int pkA0[8], pkA1[8], pkB0[8], pkB1[8];                   \
        _Pragma("unroll")                                                  \
        for (int p = 0; p < 8; ++p) {                                      \
            const auto eA0 = __builtin_amdgcn_cvt_pkrtz(                   \
                __builtin_amdgcn_exp2f(s0A[2 * p]),                        \
                __builtin_amdgcn_exp2f(s0A[2 * p + 1]));                   \
            const auto eA1 = __builtin_amdgcn_cvt_pkrtz(                   \
                __builtin_amdgcn_exp2f(s1A[2 * p]),                        \
                __builtin_amdgcn_exp2f(s1A[2 * p + 1]));                   \
            pkA0[p] = __builtin_bit_cast(unsigned int, eA0);               \
            pkA1[p] = __builtin_bit_cast(unsigned int, eA1);               \
        }                                                                  \
        const uint4v uA00 = {pkA0[0], pkA0[1], pkA0[2], pkA0[3]};          \
        const uint4v uA01 = {pkA0[4], pkA0[5], pkA0[6], pkA0[7]};          \
        const uint4v uA10 = {pkA1[0], pkA1[1], pkA1[2], pkA1[3]};          \
        const uint4v uA11 = {pkA1[4], pkA1[5], pkA1[6], pkA1[7]};          \
        const half8 afA00 = __builtin_bit_cast(half8, uA00);               \
        const half8 afA01 = __builtin_bit_cast(half8, uA01);               \
        const half8 afA10 = __builtin_bit_cast(half8, uA10);               \
        const half8 afA11 = __builtin_bit_cast(half8, uA11);               \
        /* Phase 3: PV-A MFMAs interleaved with exp-B VALU */              \
        lacA = MFMA32(afA00 + afA01, ones, lacA);                          \
        EXPB(0); EXPB(1);                                                  \
        o0A = MFMA32(afA00, vbl[0], o0A);                                  \
        EXPB(2);                                                           \
        o1A = MFMA32(afA00, vbh[0], o1A);                                  \
        EXPB(3);                                                           \
        o0A = MFMA32(afA01, vbl[1], o0A);                                  \
        EXPB(4);                                                           \
        o1A = MFMA32(afA01, vbh[1], o1A);                                  \
        EXPB(5);                                                           \
        lacA = MFMA32(afA10 + afA11, ones, lacA);                          \
        EXPB(6);                                                           \
        o0A = MFMA32(afA10, vbl[2], o0A);                                  \
        EXPB(7);                                                           \
        o1A = MFMA32(afA10, vbh[2], o1A);                                  \
        o0A = MFMA32(afA11, vbl[3], o0A);                                  \
        o1A = MFMA32(afA11, vbh[3], o1A);                                  \
        /* Phase 4: PV-B */                                                \
        const uint4v uB00 = {pkB0[0], pkB0[1], pkB0[2], pkB0[3]};          \
        const uint4v uB01 = {pkB0[4], pkB0[5], pkB0[6], pkB0[7]};          \
        const uint4v uB10 = {pkB1[0], pkB1[1], pkB1[2], pkB1[3]};          \
        const uint4v uB11 = {pkB1[4], pkB1[5], pkB1[6], pkB1[7]};          \
        const half8 afB00 = __builtin_bit_cast(half8, uB00);               \
        const half8 afB01 = __builtin_bit_cast(half8, uB01);               \
        const half8 afB10 = __builtin_bit_cast(half8, uB10);               \
        const half8 afB11 = __builtin_bit_cast(half8, uB11);               \
        lacB = MFMA32(afB00 + afB01, ones, lacB);                          \
        o0B = MFMA32(afB00, vbl[0], o0B);                                  \
        o1B = MFMA32(afB00, vbh[0], o1B);                                  \
        o0B = MFMA32(afB01, vbl[1], o0B);                                  \
        o1B = MFMA32(afB01, vbh[1], o1B);                                  \
        lacB = MFMA32(afB10 + afB11, ones, lacB);                          \
        o0B = MFMA32(afB10, vbl[2], o0B);                                  \
        o1B = MFMA32(afB10, vbh[2], o1B);                                  \
        o0B = MFMA32(afB11, vbl[3], o0B);                                  \
        o1B = MFMA32(afB11, vbh[3], o1B);                                  \
    } while (0)

    // ---- prologue: stage tile 0 into buffer 0, drain ----
    STAGE(Kl0, Vl0);
    __syncthreads();   // tile 0 staged (implicit vmcnt(0) before s_barrier)

    // ---- main loop: 2 tiles/iter, static ping-pong, 1 barrier/tile ----
    for (int it = 0; it < 15; ++it) {
        STAGE(Kl1, Vl1);        // tile 2it+1
        COMPUTE(Kl0, Vl0);      // tile 2it
        __syncthreads();
        STAGE(Kl0, Vl0);        // tile 2it+2
        COMPUTE(Kl1, Vl1);      // tile 2it+1
        __syncthreads();
    }
    STAGE(Kl1, Vl1);            // tile 31
    COMPUTE(Kl0, Vl0);          // tile 30
    __syncthreads();
    COMPUTE(Kl1, Vl1);          // tile 31 (no prefetch)

#undef STAGE
#undef COMPUTE
#undef EXPB

    // ---- epilogue: rows of o/lac coincide -> no cross-lane needed ----
    float* obA = outg + ((size_t)bh * S_LEN + qblk * 256 + w * 32) * D_DIM;
    float* obB = obA + (size_t)128 * D_DIM;
#pragma unroll
    for (int reg = 0; reg < 16; ++reg) {
        const int q = (reg & 3) + 8 * (reg >> 2) + 4 * h;
        const float invA = 1.0f / lacA[reg];
        const float invB = 1.0f / lacB[reg];
        obA[(size_t)q * D_DIM + lq]      = o0A[reg] * invA;
        obA[(size_t)q * D_DIM + 32 + lq] = o1A[reg] * invA;
        obB[(size_t)q * D_DIM + lq]      = o0B[reg] * invB;
        obB[(size_t)q * D_DIM + 32 + lq] = o1B[reg] * invB;
    }
}

extern "C" void kernel_launch(void* const* d_in, const int* in_sizes, int n_in,
                              void* d_out, int out_size, void* d_ws, size_t ws_size,
                              hipStream_t stream) {
    const float* q = (const float*)d_in[0];
    const float* k = (const float*)d_in[1];
    const float* v = (const float*)d_in[2];
    float* out = (float*)d_out;
    (void)in_sizes; (void)n_in; (void)out_size; (void)ws_size;

    _Float16* kh = (_Float16*)d_ws;                       // 16.78 MB
    _Float16* vt = kh + (size_t)N_BH * S_LEN * D_DIM;     // 16.78 MB

    prep_kernel<<<dim3(S_LEN / 128, N_BH), dim3(256), 0, stream>>>(k, v, kh, vt);
    fa_kernel<<<dim3(512), dim3(256), 0, stream>>>(q, kh, vt, out);
}

// Round 6
// 200.310 us; speedup vs baseline: 1.1533x; 1.1533x over previous
//
#include <hip/hip_runtime.h>

// Scaled dot-product attention, B=4 H=16 S=2048 D=64, fp32 in/out.
// R12: (a) fa COMPUTE reverted to R9's exact register schedule -- R11's
// interleaved variant spilled to scratch (FETCH +25MB, WRITE +42MB of
// scratch traffic, dur 89.5->119.6, MfmaUtil 38->27). (b) keep R10/R11's
// rewritten prep (correct; complement unchanged 113->111 across two very
// different preps => complement is mostly fixed harness restore work, not
// a lever). (c) ONE new lever: T5 s_setprio(1) around MFMA clusters --
// 2 independent blocks/CU run phase-shifted, priority keeps the matrix
// pipe fed while the other block is in its exp/VALU phase (catalog: +4-7%
// on attn). Ping-pong pipeline, GLL16 swizzle, exp2 scale unchanged.

#define S_LEN 2048
#define D_DIM 64
#define N_BH  64
#define QSCALE 0.18033688011112042f  // (1/sqrt(64)) * log2(e)

typedef _Float16 half8 __attribute__((ext_vector_type(8)));
typedef _Float16 half4 __attribute__((ext_vector_type(4)));
typedef float floatx16 __attribute__((ext_vector_type(16)));
typedef unsigned int uint4v __attribute__((ext_vector_type(4)));

#define MFMA32(a, b, c) __builtin_amdgcn_mfma_f32_32x32x16_f16((a), (b), (c), 0, 0, 0)

#define GLL16(g, l) __builtin_amdgcn_global_load_lds(                      \
    (const __attribute__((address_space(1))) void*)(g),                    \
    (__attribute__((address_space(3))) void*)(l), 16, 0, 0)

// ---- pre-pass: K fp32 -> f16 (same layout, streaming); V fp32 -> f16
// transposed to [bh][d][s'] where s' = s with bits 2<->3 swapped.
// Tile 128s x 64d. LDS [d][slot] stride 132 f16 (4-way max on the
// transposed column writes); 256B-coalesced vt stores.
__global__ __launch_bounds__(256) void prep_kernel(
    const float* __restrict__ kg, const float* __restrict__ vg,
    _Float16* __restrict__ kh, _Float16* __restrict__ vt)
{
    __shared__ _Float16 Ls[64 * 132];
    const int tid = threadIdx.x;
    const int bh = blockIdx.y;
    const int sbase = blockIdx.x * 128;
    const size_t gbase = ((size_t)(bh * S_LEN + sbase)) * D_DIM;  // 8192 floats

    // K: pure convert, fully coalesced both sides.
#pragma unroll
    for (int i = 0; i < 8; ++i) {
        const int e = i * 1024 + tid * 4;
        const float4 kv = *(const float4*)(kg + gbase + e);
        half4 hk;
        hk[0] = (_Float16)kv.x; hk[1] = (_Float16)kv.y;
        hk[2] = (_Float16)kv.z; hk[3] = (_Float16)kv.w;
        *(half4*)(kh + gbase + e) = hk;
    }
    // V: coalesced load, transposed scalar LDS write at sp-permuted slot.
#pragma unroll
    for (int i = 0; i < 8; ++i) {
        const int e = i * 1024 + tid * 4;
        const int s = e >> 6, d0 = e & 63;
        const float4 vv = *(const float4*)(vg + gbase + e);
        const int sp = (s & ~12) | ((s & 4) << 1) | ((s & 8) >> 1);  // b2<->b3
        Ls[(d0 + 0) * 132 + sp] = (_Float16)vv.x;
        Ls[(d0 + 1) * 132 + sp] = (_Float16)vv.y;
        Ls[(d0 + 2) * 132 + sp] = (_Float16)vv.z;
        Ls[(d0 + 3) * 132 + sp] = (_Float16)vv.w;
    }
    __syncthreads();
    // write out: 64 d-rows x 128 f16; wave w owns rows [w*16, w*16+16).
    const int w = tid >> 6, L = tid & 63;
    const int dr = L >> 4;        // row within 4-row group
    const int c  = L & 15;        // 16B chunk within row
#pragma unroll
    for (int k = 0; k < 4; ++k) {
        const int d = w * 16 + k * 4 + dr;
        const half4 lo = *(const half4*)&Ls[d * 132 + c * 8];
        const half4 hi = *(const half4*)&Ls[d * 132 + c * 8 + 4];
        half8 o;
        o[0] = lo[0]; o[1] = lo[1]; o[2] = lo[2]; o[3] = lo[3];
        o[4] = hi[0]; o[5] = hi[1]; o[6] = hi[2]; o[7] = hi[3];
        *(half8*)(vt + ((size_t)(bh * D_DIM + d)) * S_LEN + sbase + c * 8) = o;
    }
}

// ---- main flash kernel: 4 waves x 64 q = 256 q per block; K-tiles of 64
__global__ __launch_bounds__(256, 2) void fa_kernel(
    const float* __restrict__ qg, const _Float16* __restrict__ kh,
    const _Float16* __restrict__ vt, float* __restrict__ outg)
{
    // Static double buffers. [row][phys 16B chunk], phys = logical ^ (row&7).
    __shared__ _Float16 Kl0[64 * 64];   // [key][d]
    __shared__ _Float16 Kl1[64 * 64];
    __shared__ _Float16 Vl0[64 * 64];   // [d][pos]  (pos = permuted key)
    __shared__ _Float16 Vl1[64 * 64];

    const int tid = threadIdx.x;
    const int w = tid >> 6;            // wave 0..3
    const int L = tid & 63;
    const int lq = L & 31;
    const int h = L >> 5;

    // 512 blocks; XCD ~ id&7 -> bh 8c..8c+7 on XCD c (4MB f16 KV fits L2)
    const int id = blockIdx.x;
    const int bh   = ((id & 7) << 3) | (id >> 6);
    const int qblk = (id >> 3) & 7;    // 8 q-blocks of 256 q
    const int qrowA = qblk * 256 + w * 32 + lq;

    // Q fragments (B operand of S^T): B[k=d][n=q], k = 16*ks + 8*h + j
    half8 qbA[4], qbB[4];
    {
        const float* qpA = qg + ((size_t)bh * S_LEN + qrowA) * D_DIM + h * 8;
        const float* qpB = qpA + 128 * D_DIM;
#pragma unroll
        for (int ks = 0; ks < 4; ++ks) {
            const float4 a0 = *(const float4*)(qpA + ks * 16);
            const float4 b0 = *(const float4*)(qpA + ks * 16 + 4);
            const float4 a1 = *(const float4*)(qpB + ks * 16);
            const float4 b1 = *(const float4*)(qpB + ks * 16 + 4);
            qbA[ks][0] = (_Float16)(a0.x * QSCALE);
            qbA[ks][1] = (_Float16)(a0.y * QSCALE);
            qbA[ks][2] = (_Float16)(a0.z * QSCALE);
            qbA[ks][3] = (_Float16)(a0.w * QSCALE);
            qbA[ks][4] = (_Float16)(b0.x * QSCALE);
            qbA[ks][5] = (_Float16)(b0.y * QSCALE);
            qbA[ks][6] = (_Float16)(b0.z * QSCALE);
            qbA[ks][7] = (_Float16)(b0.w * QSCALE);
            qbB[ks][0] = (_Float16)(a1.x * QSCALE);
            qbB[ks][1] = (_Float16)(a1.y * QSCALE);
            qbB[ks][2] = (_Float16)(a1.z * QSCALE);
            qbB[ks][3] = (_Float16)(a1.w * QSCALE);
            qbB[ks][4] = (_Float16)(b1.x * QSCALE);
            qbB[ks][5] = (_Float16)(b1.y * QSCALE);
            qbB[ks][6] = (_Float16)(b1.z * QSCALE);
            qbB[ks][7] = (_Float16)(b1.w * QSCALE);
        }
    }

    floatx16 o0A, o1A, lacA, o0B, o1B, lacB;
#pragma unroll
    for (int r = 0; r < 16; ++r) {
        o0A[r] = 0.f; o1A[r] = 0.f; lacA[r] = 0.f;
        o0B[r] = 0.f; o1B[r] = 0.f; lacB[r] = 0.f;
    }

    half8 ones;
#pragma unroll
    for (int j = 0; j < 8; ++j) ones[j] = (_Float16)1.0f;

    // staging: wave w covers rows [w*16, w*16+16), 2 GLL16 each for K and V.
    const int rloc = L >> 3, lc = L & 7;
    const int crd = lc ^ rloc;
    const _Float16* kgl = kh + (size_t)bh * S_LEN * D_DIM
                        + (size_t)(w * 16 + rloc) * D_DIM + crd * 8;
    const _Float16* vgl = vt + (size_t)bh * D_DIM * S_LEN
                        + (size_t)(w * 16 + rloc) * S_LEN + crd * 8;
    const int woff = w * 16 * 64;

#define STAGE(KD, VD) do {                                                 \
        GLL16(kgl,                     &KD[woff]);                         \
        GLL16(kgl + (size_t)8 * D_DIM, &KD[woff + 8 * 64]);                \
        GLL16(vgl,                     &VD[woff]);                         \
        GLL16(vgl + (size_t)8 * S_LEN, &VD[woff + 8 * 64]);                \
        kgl += 64 * D_DIM;                                                 \
        vgl += 64;                                                         \
    } while (0)

#define COMPUTE(KB, VB) do {                                               \
        /* S^T = K Q^T for both q-groups; K fragments read ONCE */         \
        floatx16 s0A, s1A, s0B, s1B;                                       \
        _Pragma("unroll")                                                  \
        for (int r = 0; r < 16; ++r) {                                     \
            s0A[r] = 0.f; s1A[r] = 0.f; s0B[r] = 0.f; s1B[r] = 0.f;        \
        }                                                                  \
        __builtin_amdgcn_s_setprio(1);                                     \
        _Pragma("unroll")                                                  \
        for (int ks = 0; ks < 4; ++ks) {                                   \
            const int sw = (((2 * ks + h) ^ (lq & 7)) << 3);               \
            const half8 ka0 = *(const half8*)&KB[lq * 64 + sw];            \
            const half8 ka1 = *(const half8*)&KB[(32 + lq) * 64 + sw];     \
            s0A = MFMA32(ka0, qbA[ks], s0A);                               \
            s1A = MFMA32(ka1, qbA[ks], s1A);                               \
            s0B = MFMA32(ka0, qbB[ks], s0B);                               \
            s1B = MFMA32(ka1, qbB[ks], s1B);                               \
        }                                                                  \
        __builtin_amdgcn_s_setprio(0);                                     \
        /* P = exp2(S^T); pk regs ARE the A-fragments */                   \
        unsigned int pkA0[8], pkA1[8], pkB0[8], pkB1[8];                   \
        _Pragma("unroll")                                                  \
        for (int p = 0; p < 8; ++p) {                                      \
            const auto eA0 = __builtin_amdgcn_cvt_pkrtz(                   \
                __builtin_amdgcn_exp2f(s0A[2 * p]),                        \
                __builtin_amdgcn_exp2f(s0A[2 * p + 1]));                   \
            const auto eA1 = __builtin_amdgcn_cvt_pkrtz(                   \
                __builtin_amdgcn_exp2f(s1A[2 * p]),                        \
                __builtin_amdgcn_exp2f(s1A[2 * p + 1]));                   \
            pkA0[p] = __builtin_bit_cast(unsigned int, eA0);               \
            pkA1[p] = __builtin_bit_cast(unsigned int, eA1);               \
        }                                                                  \
        _Pragma("unroll")                                                  \
        for (int p = 0; p < 8; ++p) {                                      \
            const auto eB0 = __builtin_amdgcn_cvt_pkrtz(                   \
                __builtin_amdgcn_exp2f(s0B[2 * p]),                        \
                __builtin_amdgcn_exp2f(s0B[2 * p + 1]));                   \
            const auto eB1 = __builtin_amdgcn_cvt_pkrtz(                   \
                __builtin_amdgcn_exp2f(s1B[2 * p]),                        \
                __builtin_amdgcn_exp2f(s1B[2 * p + 1]));                   \
            pkB0[p] = __builtin_bit_cast(unsigned int, eB0);               \
            pkB1[p] = __builtin_bit_cast(unsigned int, eB1);               \
        }                                                                  \
        /* O += P V ; lac += (af0+af1) * ones; V fragments read ONCE */    \
        __builtin_amdgcn_s_setprio(1);                                     \
        _Pragma("unroll")                                                  \
        for (int mt = 0; mt < 2; ++mt) {                                   \
            const unsigned int* pA = mt ? pkA1 : pkA0;                     \
            const unsigned int* pB = mt ? pkB1 : pkB0;                     \
            const uint4v uA0 = {pA[0], pA[1], pA[2], pA[3]};               \
            const uint4v uA1 = {pA[4], pA[5], pA[6], pA[7]};               \
            const uint4v uB0 = {pB[0], pB[1], pB[2], pB[3]};               \
            const uint4v uB1 = {pB[4], pB[5], pB[6], pB[7]};               \
            const half8 afA0 = __builtin_bit_cast(half8, uA0);             \
            const half8 afA1 = __builtin_bit_cast(half8, uA1);             \
            const half8 afB0 = __builtin_bit_cast(half8, uB0);             \
            const half8 afB1 = __builtin_bit_cast(half8, uB1);             \
            lacA = MFMA32(afA0 + afA1, ones, lacA);                        \
            lacB = MFMA32(afB0 + afB1, ones, lacB);                        \
            _Pragma("unroll")                                              \
            for (int kl = 0; kl < 2; ++kl) {                               \
                const int ksg = mt * 2 + kl;                               \
                const int sw = (((2 * ksg + h) ^ (lq & 7)) << 3);          \
                const half8 vb0 = *(const half8*)&VB[lq * 64 + sw];        \
                const half8 vb1 = *(const half8*)&VB[(32 + lq) * 64 + sw]; \
                const half8 afA = kl ? afA1 : afA0;                        \
                const half8 afB = kl ? afB1 : afB0;                        \
                o0A = MFMA32(afA, vb0, o0A);                               \
                o1A = MFMA32(afA, vb1, o1A);                               \
                o0B = MFMA32(afB, vb0, o0B);                               \
                o1B = MFMA32(afB, vb1, o1B);                               \
            }                                                              \
        }                                                                  \
        __builtin_amdgcn_s_setprio(0);                                     \
    } while (0)

    // ---- prologue: stage tile 0 into buffer 0, drain ----
    STAGE(Kl0, Vl0);
    __syncthreads();   // tile 0 staged (implicit vmcnt(0) before s_barrier)

    // ---- main loop: 2 tiles/iter, static ping-pong, 1 barrier/tile ----
    for (int it = 0; it < 15; ++it) {
        STAGE(Kl1, Vl1);        // tile 2it+1
        COMPUTE(Kl0, Vl0);      // tile 2it
        __syncthreads();
        STAGE(Kl0, Vl0);        // tile 2it+2
        COMPUTE(Kl1, Vl1);      // tile 2it+1
        __syncthreads();
    }
    // tiles 0..29 computed; tile 30 staged in buf0
    STAGE(Kl1, Vl1);            // tile 31
    COMPUTE(Kl0, Vl0);          // tile 30
    __syncthreads();
    COMPUTE(Kl1, Vl1);          // tile 31 (no prefetch)

#undef STAGE
#undef COMPUTE

    // ---- epilogue: rows of o/lac coincide -> no cross-lane needed ----
    float* obA = outg + ((size_t)bh * S_LEN + qblk * 256 + w * 32) * D_DIM;
    float* obB = obA + (size_t)128 * D_DIM;
#pragma unroll
    for (int reg = 0; reg < 16; ++reg) {
        const int q = (reg & 3) + 8 * (reg >> 2) + 4 * h;
        const float invA = 1.0f / lacA[reg];
        const float invB = 1.0f / lacB[reg];
        obA[(size_t)q * D_DIM + lq]      = o0A[reg] * invA;
        obA[(size_t)q * D_DIM + 32 + lq] = o1A[reg] * invA;
        obB[(size_t)q * D_DIM + lq]      = o0B[reg] * invB;
        obB[(size_t)q * D_DIM + 32 + lq] = o1B[reg] * invB;
    }
}

extern "C" void kernel_launch(void* const* d_in, const int* in_sizes, int n_in,
                              void* d_out, int out_size, void* d_ws, size_t ws_size,
                              hipStream_t stream) {
    const float* q = (const float*)d_in[0];
    const float* k = (const float*)d_in[1];
    const float* v = (const float*)d_in[2];
    float* out = (float*)d_out;
    (void)in_sizes; (void)n_in; (void)out_size; (void)ws_size;

    _Float16* kh = (_Float16*)d_ws;                       // 16.78 MB
    _Float16* vt = kh + (size_t)N_BH * S_LEN * D_DIM;     // 16.78 MB

    prep_kernel<<<dim3(S_LEN / 128, N_BH), dim3(256), 0, stream>>>(k, v, kh, vt);
    fa_kernel<<<dim3(512), dim3(256), 0, stream>>>(q, kh, vt, out);
}